// Round 12
// baseline (506.537 us; speedup 1.0000x reference)
//
#include <hip/hip_runtime.h>

// FullFixedTimeCausalConstructiveAttention — MFMA flash, SPLIT-K + in-kernel merge.
// B=8, L=1024, H=8, E=64, HIST=512. Inputs fp32, output fp32.
// Layout: (b, l, h, e) row-major; per-(b,h) row stride = H*E = 512 floats.
//
// R12: R11 falsified "barriers are the wall" (no-LDS = 2.5x worse; staging is
// load-bearing). R4's floor is throughput-with-too-few-streams: 26% occupancy
// is exactly the grid-drain average. Lever: waves/CU.
//  - qt>=8 blocks split into 2 K-range halves -> 1536 blocks, <=8 iters each,
//    ~6 blocks/CU resident = ~24 waves/CU (VGPR pinned <=64 via launch_bounds:
//    the m69 occupancy cliff is at 64).
//  - split1 owns the diag tile (zdiag, pd). Partials (unnormalized O^T, m, l,
//    pd) -> d_ws; LAST-arriving split block merges (atomicAdd flag +
//    threadfence, no spin). Flags zeroed by hipMemsetAsync each launch.
//  - both splits of one (bh,qt) have blockIdx differing by 64 (mult. of 8) ->
//    same XCD -> partner partial is L2-hot.
#define LL   1024
#define HH   8
#define EE   64
#define KSTR 72      // f16 LDS row stride: 144 B = 16B-aligned
#define PSTR 4352    // floats per ws partial (4096 O + 64 m + 64 l + 64 pd, padded)
#define PBASE 1024   // float offset of partials in ws (first 4KB = flags)

#define SCALE2 0.18033688011112043f   // (1/sqrt(64)) * log2(e)

typedef _Float16 f16;
typedef _Float16 v8h  __attribute__((ext_vector_type(8)));
typedef _Float16 h2   __attribute__((ext_vector_type(2)));
typedef float    v4f  __attribute__((ext_vector_type(4)));
typedef int      v2i  __attribute__((ext_vector_type(2)));

__device__ __forceinline__ float fexp2(float x) {
#if __has_builtin(__builtin_amdgcn_exp2f)
  return __builtin_amdgcn_exp2f(x);
#else
  return __expf(x * 0.6931471805599453f);
#endif
}

__device__ __forceinline__ h2 pkh2(float a, float b) {
#if __has_builtin(__builtin_amdgcn_cvt_pkrtz)
  return __builtin_bit_cast(h2, __builtin_amdgcn_cvt_pkrtz(a, b));
#else
  h2 r; r[0] = (f16)a; r[1] = (f16)b; return r;
#endif
}

// Reduce across the 4 lane-quarters (lanes ln, ln+16, ln+32, ln+48).
__device__ __forceinline__ float red4max(float x) {
#if __has_builtin(__builtin_amdgcn_permlane16_swap) && __has_builtin(__builtin_amdgcn_permlane32_swap)
  int xi = __float_as_int(x);
  v2i a = __builtin_amdgcn_permlane16_swap(xi, xi, false, false);
  float m = fmaxf(__int_as_float(a.x), __int_as_float(a.y));
  int mi = __float_as_int(m);
  v2i b = __builtin_amdgcn_permlane32_swap(mi, mi, false, false);
  return fmaxf(__int_as_float(b.x), __int_as_float(b.y));
#else
  x = fmaxf(x, __shfl_xor(x, 16));
  return fmaxf(x, __shfl_xor(x, 32));
#endif
}

__device__ __forceinline__ float red4sum(float x) {
#if __has_builtin(__builtin_amdgcn_permlane16_swap) && __has_builtin(__builtin_amdgcn_permlane32_swap)
  int xi = __float_as_int(x);
  v2i a = __builtin_amdgcn_permlane16_swap(xi, xi, false, false);
  float s = __int_as_float(a.x) + __int_as_float(a.y);
  int si = __float_as_int(s);
  v2i b = __builtin_amdgcn_permlane32_swap(si, si, false, false);
  return __int_as_float(b.x) + __int_as_float(b.y);
#else
  x += __shfl_xor(x, 16);
  return x + __shfl_xor(x, 32);
#endif
}

__device__ __forceinline__ void load16f(const float* __restrict__ p, float* __restrict__ f) {
  const float4* p4 = reinterpret_cast<const float4*>(p);
  float4 a = p4[0], b = p4[1], c = p4[2], d = p4[3];
  f[0]=a.x;  f[1]=a.y;  f[2]=a.z;  f[3]=a.w;
  f[4]=b.x;  f[5]=b.y;  f[6]=b.z;  f[7]=b.w;
  f[8]=c.x;  f[9]=c.y;  f[10]=c.z; f[11]=c.w;
  f[12]=d.x; f[13]=d.y; f[14]=d.z; f[15]=d.w;
}

__device__ __forceinline__ void load8f(const float* __restrict__ p, float* __restrict__ f) {
  const float4* p4 = reinterpret_cast<const float4*>(p);
  float4 a = p4[0], b = p4[1];
  f[0]=a.x; f[1]=a.y; f[2]=a.z; f[3]=a.w;
  f[4]=b.x; f[5]=b.y; f[6]=b.z; f[7]=b.w;
}

struct TileState {
  v4f   o[4];      // O^T: lane holds O[d=16nb+4lq+r][q = tile_base + w*16 + ln]
  float m, l, pd;  // per-lane stats for q = ln
};

// One K-tile update. Lane (ln,lq) owns z[q=w*16+ln][s=sigma(nb,4lq+r)].
__device__ __forceinline__ void tile_update(
    TileState& st, const v8h* __restrict__ qf, bool dt, bool drawn,
    const f16* __restrict__ Ks, const f16* __restrict__ Vt,
    const float* __restrict__ zd,
    int w, int ln, int lq,
    const int* __restrict__ rk, const int* __restrict__ kb)
{
  // ---- S^T = K Q^T with permuted K rows: mfma nb, A-row m=ln <- K row rk[nb] ----
  v4f S[4];
#pragma unroll
  for (int nb = 0; nb < 4; ++nb) {
    const f16* krow = &Ks[rk[nb] * KSTR + 8 * lq];
    v8h k0 = *reinterpret_cast<const v8h*>(krow);
    v8h k1 = *reinterpret_cast<const v8h*>(krow + 32);
    v4f acc = (v4f){0.f, 0.f, 0.f, 0.f};
    acc = __builtin_amdgcn_mfma_f32_16x16x32_f16(k0, qf[0], acc, 0, 0, 0);
    acc = __builtin_amdgcn_mfma_f32_16x16x32_f16(k1, qf[1], acc, 0, 0, 0);
    S[nb] = acc;
  }

  float z[4][4];
#pragma unroll
  for (int nb = 0; nb < 4; ++nb)
#pragma unroll
    for (int r = 0; r < 4; ++r) z[nb][r] = S[nb][r] * SCALE2;

  const int qlocal = w * 16 + ln;
  if (dt) {
    const float zdq = drawn ? zd[qlocal] : 0.f;
#pragma unroll
    for (int nb = 0; nb < 4; ++nb) {
#pragma unroll
      for (int r = 0; r < 4; ++r) {
        const int kl = kb[nb] + r;             // sigma(nb, 4lq+r)
        if (kl > qlocal)                 z[nb][r] = -1e30f;  // causal mask
        else if (drawn && kl == qlocal)  z[nb][r] = zdq;     // diag replace
      }
    }
  }

  // ---- online softmax: local 16-tree + 2 permlane swaps (q=ln lane-local) ----
  float a0 = fmaxf(fmaxf(z[0][0], z[0][1]), fmaxf(z[0][2], z[0][3]));
  float a1 = fmaxf(fmaxf(z[1][0], z[1][1]), fmaxf(z[1][2], z[1][3]));
  float a2 = fmaxf(fmaxf(z[2][0], z[2][1]), fmaxf(z[2][2], z[2][3]));
  float a3 = fmaxf(fmaxf(z[3][0], z[3][1]), fmaxf(z[3][2], z[3][3]));
  const float mx = red4max(fmaxf(fmaxf(a0, a1), fmaxf(a2, a3)));

  const float mn = fmaxf(st.m, mx);
  const float al = fexp2(st.m - mn);
  st.m = mn;

  float p[4][4], rsum = 0.f, pdl = 0.f;
#pragma unroll
  for (int nb = 0; nb < 4; ++nb) {
#pragma unroll
    for (int r = 0; r < 4; ++r) {
      const float pv = fexp2(z[nb][r] - mn);
      p[nb][r] = pv;
      rsum += pv;
      if (dt && drawn && (kb[nb] + r) == qlocal) pdl = pv;
    }
  }
  rsum = red4sum(rsum);
  if (dt && drawn) st.pd = red4sum(pdl);   // diag tile is split1's last: no later rescale
  st.l = st.l * al + rsum;
#pragma unroll
  for (int nb = 0; nb < 4; ++nb)
#pragma unroll
    for (int r = 0; r < 4; ++r) st.o[nb][r] *= al;   // per-lane scalar rescale

  // ---- P -> B-fragment in-register: owned pairs == needed k-layout by sigma ----
  h2 wq[4][2];
#pragma unroll
  for (int nb = 0; nb < 4; ++nb) {
    wq[nb][0] = pkh2(p[nb][0], p[nb][1]);
    wq[nb][1] = pkh2(p[nb][2], p[nb][3]);
  }
  const bool swp = (lq & 1);
  union U8 { v8h v; h2 h[4]; } A0, A1;
  A0.h[0] = swp ? wq[1][0] : wq[0][0];
  A0.h[1] = swp ? wq[1][1] : wq[0][1];
  A0.h[2] = swp ? wq[0][0] : wq[1][0];
  A0.h[3] = swp ? wq[0][1] : wq[1][1];
  A1.h[0] = swp ? wq[3][0] : wq[2][0];
  A1.h[1] = swp ? wq[3][1] : wq[2][1];
  A1.h[2] = swp ? wq[2][0] : wq[3][0];
  A1.h[3] = swp ? wq[2][1] : wq[3][1];

  // ---- O^T += V^T P^T: A = V-frag (d=16nb+ln), B = P-frag ----
#pragma unroll
  for (int nb = 0; nb < 4; ++nb) {
    const int d   = nb * 16 + ln;
    const int dsw = (d >> 3) & 7;
    const f16* vbase = &Vt[d * KSTR];
    v8h v0 = *reinterpret_cast<const v8h*>(vbase + (((lq    ) ^ dsw) & 7) * 8);
    v8h v1 = *reinterpret_cast<const v8h*>(vbase + (((lq + 4) ^ dsw) & 7) * 8);
    st.o[nb] = __builtin_amdgcn_mfma_f32_16x16x32_f16(v0, A0.v, st.o[nb], 0, 0, 0);
    st.o[nb] = __builtin_amdgcn_mfma_f32_16x16x32_f16(v1, A1.v, st.o[nb], 0, 0, 0);
  }
}

extern "C" __global__ __launch_bounds__(256, 8)
void ftcca_sk(const float* __restrict__ Q,  const float* __restrict__ K,
              const float* __restrict__ V,  const float* __restrict__ Qd,
              const float* __restrict__ Kd, const float* __restrict__ Vd,
              float* __restrict__ ws,       float* __restrict__ out)
{
  __shared__ f16   Ks[64 * KSTR];
  __shared__ f16   Vt[64 * KSTR];       // V tile transposed [d][s], s-chunks XOR-swizzled
  __shared__ float zdiag[64];           // diag replacement scores (log2 units)
  __shared__ int   oldflag;

  // block mapping: u<16 -> split block (qt = 15-(u>>1), s = u&1); u>=16 -> unsplit qt=23-u
  const int g   = blockIdx.x;
  const int bh  = g & 63;
  const int u   = g >> 6;               // 0..23
  int qt, s;
  if (u < 16) { qt = 15 - (u >> 1); s = u & 1; }
  else        { qt = 23 - u;        s = -1;    }
  const bool split = (s >= 0);
  const bool drawn = split;             // split blocks are exactly the qt>=8 (l>=512) rows
  const int b   = bh >> 3, h = bh & 7;
  const int t   = threadIdx.x;
  const int w    = t >> 6;
  const int lane = t & 63;
  const int ln   = lane & 15;
  const int lq   = lane >> 4;
  const int rs   = t >> 2;              // K staging row 0..63
  const int es0  = (t & 3) * 16;        // K staging dim offset
  const int vr0  = (t >> 3) * 2;        // V staging row pair 0..62
  const int vd0  = (t & 7) * 8;         // V staging dim offset

  const size_t base = ((size_t)b * LL * HH + h) * EE;
  const int ROWF = HH * EE;             // 512

  // K-range for this block
  const int n  = qt + 1;
  const int i0 = (s == 1) ? (n >> 1) : 0;
  const int i1 = (s == 0) ? (n >> 1) : n;

  // sigma tables: K-frag read rows (indexed by ln) and owned-k bases (indexed by lq)
  const int q2 = ln >> 2;
  int rk[4], kb[4];
  rk[0] = ln + ((q2 + 1) >> 1) * 8;     // off[0] = {0,8,8,16}
  rk[1] = ln + 4 + (q2 >> 1) * 8;       // off[1] = {4,4,12,12}
  rk[2] = rk[0] + 32;
  rk[3] = rk[1] + 32;
  kb[0] = 4 * lq + ((lq + 1) >> 1) * 8;
  kb[1] = 4 * lq + 4 + (lq >> 1) * 8;
  kb[2] = kb[0] + 32;
  kb[3] = kb[1] + 32;

  // ---- zdiag (split1 only — it owns the diag tile): z[l][l] = SCALE2*(Qd[l].Kd[l]) ----
  if (s == 1) {
    const int l = qt * 64 + rs;
    const float* qrow = Qd + base + (size_t)l * ROWF + es0;
    const float* krow = Kd + base + (size_t)l * ROWF + es0;
    float par = 0.f;
#pragma unroll
    for (int i = 0; i < 16; ++i) par += qrow[i] * krow[i];
    par += __shfl_xor(par, 1);
    par += __shfl_xor(par, 2);
    if ((t & 3) == 0) zdiag[rs] = SCALE2 * par;
  }

  // ---- Q fragments (B-operand of QK^T: free-dim=ln, k=32c+8lq+j) ----
  const int qlocal = w * 16 + ln;
  const float* qsrc = drawn ? Qd : Q;
  v8h qf[2];
  {
    const float* pq = qsrc + base + (size_t)(qt * 64 + qlocal) * ROWF;
#pragma unroll
    for (int c = 0; c < 2; ++c) {
      const float* x = pq + 32 * c + 8 * lq;
#pragma unroll
      for (int j = 0; j < 8; ++j) qf[c][j] = (f16)x[j];
    }
  }

  TileState st;
#pragma unroll
  for (int nb = 0; nb < 4; ++nb) st.o[nb] = (v4f){0, 0, 0, 0};
  st.m = -1e30f; st.l = 0.f; st.pd = 0.f;

  // ---- prefetch K/V tile i0 into registers ----
  float tk[16], tv[16];
  load16f(K + base + (size_t)(i0 * 64 + rs) * ROWF + es0, tk);
  load8f(V + base + (size_t)(i0 * 64 + vr0) * ROWF + vd0, tv);
  load8f(V + base + (size_t)(i0 * 64 + vr0 + 1) * ROWF + vd0, tv + 8);

  for (int i = i0; i < i1; ++i) {
    __syncthreads();   // previous tile's LDS fully consumed
    {
      // commit register-staged tile i to LDS (f16)
      v8h k0, k1;
#pragma unroll
      for (int j = 0; j < 8; ++j) { k0[j] = (f16)tk[j]; k1[j] = (f16)tk[8 + j]; }
      v8h* kd0 = reinterpret_cast<v8h*>(&Ks[rs * KSTR + es0]);
      kd0[0] = k0;
      kd0[1] = k1;
      // V transposed: element (s=vr0+j, d) -> Vt[d*KSTR + ((s>>3)^(d>>3))*8 + (s&7)]
      const int vswz = vr0 >> 3;
#pragma unroll
      for (int dd = 0; dd < 8; ++dd) {
        const int d  = vd0 + dd;
        const int ch = (vswz ^ (d >> 3)) & 7;
        h2 val; val[0] = (f16)tv[dd]; val[1] = (f16)tv[8 + dd];
        *reinterpret_cast<h2*>(&Vt[d * KSTR + ch * 8 + (vr0 & 7)]) = val;
      }
    }
    __syncthreads();

    // issue next tile's global loads; they fly under this tile's compute
    if (i + 1 < i1) {
      const size_t r0 = (size_t)((i + 1) * 64);
      load16f(K + base + (r0 + rs) * ROWF + es0, tk);
      load8f(V + base + (r0 + vr0) * ROWF + vd0, tv);
      load8f(V + base + (r0 + vr0 + 1) * ROWF + vd0, tv + 8);
    }

    tile_update(st, qf, i == qt, drawn, Ks, Vt, zdiag, w, ln, lq, rk, kb);
  }

  const int lrow = qt * 64 + qlocal;

  if (!split) {
    // ---- unsplit epilogue (qt<=7: no drawn correction) ----
    const float inv = 1.f / st.l;
#pragma unroll
    for (int nb = 0; nb < 4; ++nb) {
      const int d0 = nb * 16 + lq * 4;
      const size_t gaddr = base + (size_t)lrow * ROWF + d0;
      float4 o4;
      o4.x = st.o[nb][0] * inv;
      o4.y = st.o[nb][1] * inv;
      o4.z = st.o[nb][2] * inv;
      o4.w = st.o[nb][3] * inv;
      *reinterpret_cast<float4*>(out + gaddr) = o4;
    }
    return;
  }

  // ---- split epilogue: publish partial, last arriver merges ----
  const int pair = (bh << 3) + (qt - 8);          // 0..511
  {
    float* Pm = ws + PBASE + (size_t)(pair * 2 + s) * PSTR;
#pragma unroll
    for (int nb = 0; nb < 4; ++nb) {
      float4 o4;
      o4.x = st.o[nb][0]; o4.y = st.o[nb][1]; o4.z = st.o[nb][2]; o4.w = st.o[nb][3];
      *reinterpret_cast<float4*>(&Pm[qlocal * 64 + nb * 16 + lq * 4]) = o4;
    }
    if (lq == 0) {
      Pm[4096 + qlocal] = st.m;
      Pm[4160 + qlocal] = st.l;
      Pm[4224 + qlocal] = st.pd;
    }
  }
  __threadfence();            // publish partial (device scope) before flag
  __syncthreads();            // all threads' writes before t0's atomic
  if (t == 0) oldflag = atomicAdd(reinterpret_cast<int*>(ws) + pair, 1);
  __syncthreads();
  if (oldflag == 0) return;   // first arriver: partner will merge

  __threadfence();            // acquire partner's partial
  const float* Pp = ws + PBASE + (size_t)(pair * 2 + (s ^ 1)) * PSTR;
  const float mb  = Pp[4096 + qlocal];
  const float lb  = Pp[4160 + qlocal];
  const float pdb = Pp[4224 + qlocal];

  const float mm = fmaxf(st.m, mb);
  const float ea = fexp2(st.m - mm);
  const float eb = fexp2(mb - mm);
  const float lt = st.l * ea + lb * eb;
  const float inv = 1.f / lt;
  const float pdinv = (st.pd * ea + pdb * eb) * inv;

#pragma unroll
  for (int nb = 0; nb < 4; ++nb) {
    const int d0 = nb * 16 + lq * 4;
    const size_t gaddr = base + (size_t)lrow * ROWF + d0;
    float4 ob = *reinterpret_cast<const float4*>(&Pp[qlocal * 64 + nb * 16 + lq * 4]);
    float4 vd4 = *reinterpret_cast<const float4*>(Vd + gaddr);
    float4 v4  = *reinterpret_cast<const float4*>(V + gaddr);
    float4 o4;
    o4.x = (st.o[nb][0] * ea + ob.x * eb) * inv + pdinv * (vd4.x - v4.x);
    o4.y = (st.o[nb][1] * ea + ob.y * eb) * inv + pdinv * (vd4.y - v4.y);
    o4.z = (st.o[nb][2] * ea + ob.z * eb) * inv + pdinv * (vd4.z - v4.z);
    o4.w = (st.o[nb][3] * ea + ob.w * eb) * inv + pdinv * (vd4.w - v4.w);
    *reinterpret_cast<float4*>(out + gaddr) = o4;
  }
}

extern "C" void kernel_launch(void* const* d_in, const int* in_sizes, int n_in,
                              void* d_out, int out_size, void* d_ws, size_t ws_size,
                              hipStream_t stream) {
  const float* q  = (const float*)d_in[0];
  const float* k  = (const float*)d_in[1];
  const float* v  = (const float*)d_in[2];
  const float* qd = (const float*)d_in[3];
  const float* kd = (const float*)d_in[4];
  const float* vd = (const float*)d_in[5];
  // d_in[6] = attn_mask (analytic), d_in[7] = history_len (HIST)
  float* out = (float*)d_out;
  float* ws  = (float*)d_ws;   // needs 4KB flags + 1024*17408B partials ~= 17.9 MB

  // zero the merge flags (graph-capture-safe; re-zeroed on every replay)
  hipMemsetAsync(d_ws, 0, 4096, stream);

  // 1536 blocks: 64 bh x (16 split-halves qt=8..15, big-first + 8 unsplit qt=7..0)
  ftcca_sk<<<dim3(1536), dim3(256), 0, stream>>>(q, k, v, qd, kd, vd, ws, out);
}

// Round 13
// 383.720 us; speedup vs baseline: 1.3201x; 1.3201x over previous
//
#include <hip/hip_runtime.h>

// FullFixedTimeCausalConstructiveAttention — MFMA flash, SPLIT-K + in-kernel merge.
// B=8, L=1024, H=8, E=64, HIST=512. Inputs fp32, output fp32.
// Layout: (b, l, h, e) row-major; per-(b,h) row stride = H*E = 512 floats.
//
// R13 = R12 with __launch_bounds__(256,4): R12's (256,8) forced total regs <=64
// on gfx950's UNIFIED VGPR/AGPR file -> VGPR=32 + full spill (WRITE_SIZE 296MB
// of scratch traffic, 400us). The split-K experiment never ran clean. This run
// isolates "more independent streams": grid 1536, <=8 iters/block, 6 blocks/CU
// resident (LDS 18.9KB and VGPR 64 both allow 8), R4's proven regalloc setting.
//  - qt>=8 blocks split into 2 K-range halves; split1 owns diag tile (zdiag,pd).
//  - Partials (unnormalized O^T, m, l, pd) -> d_ws; LAST-arriving split block
//    merges (atomicAdd flag + threadfence, no spin). Flags zeroed by
//    hipMemsetAsync each launch (graph-safe).
//  - Splits of one (bh,qt) differ by 64 in blockIdx (mult. of 8 XCDs) -> same
//    XCD -> partner partial is L2-hot.
#define LL   1024
#define HH   8
#define EE   64
#define KSTR 72      // f16 LDS row stride: 144 B = 16B-aligned
#define PSTR 4352    // floats per ws partial (4096 O + 64 m + 64 l + 64 pd, padded)
#define PBASE 1024   // float offset of partials in ws (first 4KB = flags)

#define SCALE2 0.18033688011112043f   // (1/sqrt(64)) * log2(e)

typedef _Float16 f16;
typedef _Float16 v8h  __attribute__((ext_vector_type(8)));
typedef _Float16 h2   __attribute__((ext_vector_type(2)));
typedef float    v4f  __attribute__((ext_vector_type(4)));
typedef int      v2i  __attribute__((ext_vector_type(2)));

__device__ __forceinline__ float fexp2(float x) {
#if __has_builtin(__builtin_amdgcn_exp2f)
  return __builtin_amdgcn_exp2f(x);
#else
  return __expf(x * 0.6931471805599453f);
#endif
}

__device__ __forceinline__ h2 pkh2(float a, float b) {
#if __has_builtin(__builtin_amdgcn_cvt_pkrtz)
  return __builtin_bit_cast(h2, __builtin_amdgcn_cvt_pkrtz(a, b));
#else
  h2 r; r[0] = (f16)a; r[1] = (f16)b; return r;
#endif
}

// Reduce across the 4 lane-quarters (lanes ln, ln+16, ln+32, ln+48).
__device__ __forceinline__ float red4max(float x) {
#if __has_builtin(__builtin_amdgcn_permlane16_swap) && __has_builtin(__builtin_amdgcn_permlane32_swap)
  int xi = __float_as_int(x);
  v2i a = __builtin_amdgcn_permlane16_swap(xi, xi, false, false);
  float m = fmaxf(__int_as_float(a.x), __int_as_float(a.y));
  int mi = __float_as_int(m);
  v2i b = __builtin_amdgcn_permlane32_swap(mi, mi, false, false);
  return fmaxf(__int_as_float(b.x), __int_as_float(b.y));
#else
  x = fmaxf(x, __shfl_xor(x, 16));
  return fmaxf(x, __shfl_xor(x, 32));
#endif
}

__device__ __forceinline__ float red4sum(float x) {
#if __has_builtin(__builtin_amdgcn_permlane16_swap) && __has_builtin(__builtin_amdgcn_permlane32_swap)
  int xi = __float_as_int(x);
  v2i a = __builtin_amdgcn_permlane16_swap(xi, xi, false, false);
  float s = __int_as_float(a.x) + __int_as_float(a.y);
  int si = __float_as_int(s);
  v2i b = __builtin_amdgcn_permlane32_swap(si, si, false, false);
  return __int_as_float(b.x) + __int_as_float(b.y);
#else
  x += __shfl_xor(x, 16);
  return x + __shfl_xor(x, 32);
#endif
}

__device__ __forceinline__ void load16f(const float* __restrict__ p, float* __restrict__ f) {
  const float4* p4 = reinterpret_cast<const float4*>(p);
  float4 a = p4[0], b = p4[1], c = p4[2], d = p4[3];
  f[0]=a.x;  f[1]=a.y;  f[2]=a.z;  f[3]=a.w;
  f[4]=b.x;  f[5]=b.y;  f[6]=b.z;  f[7]=b.w;
  f[8]=c.x;  f[9]=c.y;  f[10]=c.z; f[11]=c.w;
  f[12]=d.x; f[13]=d.y; f[14]=d.z; f[15]=d.w;
}

__device__ __forceinline__ void load8f(const float* __restrict__ p, float* __restrict__ f) {
  const float4* p4 = reinterpret_cast<const float4*>(p);
  float4 a = p4[0], b = p4[1];
  f[0]=a.x; f[1]=a.y; f[2]=a.z; f[3]=a.w;
  f[4]=b.x; f[5]=b.y; f[6]=b.z; f[7]=b.w;
}

struct TileState {
  v4f   o[4];      // O^T: lane holds O[d=16nb+4lq+r][q = tile_base + w*16 + ln]
  float m, l, pd;  // per-lane stats for q = ln
};

// One K-tile update. Lane (ln,lq) owns z[q=w*16+ln][s=sigma(nb,4lq+r)].
__device__ __forceinline__ void tile_update(
    TileState& st, const v8h* __restrict__ qf, bool dt, bool drawn,
    const f16* __restrict__ Ks, const f16* __restrict__ Vt,
    const float* __restrict__ zd,
    int w, int ln, int lq,
    const int* __restrict__ rk, const int* __restrict__ kb)
{
  // ---- S^T = K Q^T with permuted K rows: mfma nb, A-row m=ln <- K row rk[nb] ----
  v4f S[4];
#pragma unroll
  for (int nb = 0; nb < 4; ++nb) {
    const f16* krow = &Ks[rk[nb] * KSTR + 8 * lq];
    v8h k0 = *reinterpret_cast<const v8h*>(krow);
    v8h k1 = *reinterpret_cast<const v8h*>(krow + 32);
    v4f acc = (v4f){0.f, 0.f, 0.f, 0.f};
    acc = __builtin_amdgcn_mfma_f32_16x16x32_f16(k0, qf[0], acc, 0, 0, 0);
    acc = __builtin_amdgcn_mfma_f32_16x16x32_f16(k1, qf[1], acc, 0, 0, 0);
    S[nb] = acc;
  }

  float z[4][4];
#pragma unroll
  for (int nb = 0; nb < 4; ++nb)
#pragma unroll
    for (int r = 0; r < 4; ++r) z[nb][r] = S[nb][r] * SCALE2;

  const int qlocal = w * 16 + ln;
  if (dt) {
    const float zdq = drawn ? zd[qlocal] : 0.f;
#pragma unroll
    for (int nb = 0; nb < 4; ++nb) {
#pragma unroll
      for (int r = 0; r < 4; ++r) {
        const int kl = kb[nb] + r;             // sigma(nb, 4lq+r)
        if (kl > qlocal)                 z[nb][r] = -1e30f;  // causal mask
        else if (drawn && kl == qlocal)  z[nb][r] = zdq;     // diag replace
      }
    }
  }

  // ---- online softmax: local 16-tree + 2 permlane swaps (q=ln lane-local) ----
  float a0 = fmaxf(fmaxf(z[0][0], z[0][1]), fmaxf(z[0][2], z[0][3]));
  float a1 = fmaxf(fmaxf(z[1][0], z[1][1]), fmaxf(z[1][2], z[1][3]));
  float a2 = fmaxf(fmaxf(z[2][0], z[2][1]), fmaxf(z[2][2], z[2][3]));
  float a3 = fmaxf(fmaxf(z[3][0], z[3][1]), fmaxf(z[3][2], z[3][3]));
  const float mx = red4max(fmaxf(fmaxf(a0, a1), fmaxf(a2, a3)));

  const float mn = fmaxf(st.m, mx);
  const float al = fexp2(st.m - mn);
  st.m = mn;

  float p[4][4], rsum = 0.f, pdl = 0.f;
#pragma unroll
  for (int nb = 0; nb < 4; ++nb) {
#pragma unroll
    for (int r = 0; r < 4; ++r) {
      const float pv = fexp2(z[nb][r] - mn);
      p[nb][r] = pv;
      rsum += pv;
      if (dt && drawn && (kb[nb] + r) == qlocal) pdl = pv;
    }
  }
  rsum = red4sum(rsum);
  if (dt && drawn) st.pd = red4sum(pdl);   // diag tile is split1's last: no later rescale
  st.l = st.l * al + rsum;
#pragma unroll
  for (int nb = 0; nb < 4; ++nb)
#pragma unroll
    for (int r = 0; r < 4; ++r) st.o[nb][r] *= al;   // per-lane scalar rescale

  // ---- P -> B-fragment in-register: owned pairs == needed k-layout by sigma ----
  h2 wq[4][2];
#pragma unroll
  for (int nb = 0; nb < 4; ++nb) {
    wq[nb][0] = pkh2(p[nb][0], p[nb][1]);
    wq[nb][1] = pkh2(p[nb][2], p[nb][3]);
  }
  const bool swp = (lq & 1);
  union U8 { v8h v; h2 h[4]; } A0, A1;
  A0.h[0] = swp ? wq[1][0] : wq[0][0];
  A0.h[1] = swp ? wq[1][1] : wq[0][1];
  A0.h[2] = swp ? wq[0][0] : wq[1][0];
  A0.h[3] = swp ? wq[0][1] : wq[1][1];
  A1.h[0] = swp ? wq[3][0] : wq[2][0];
  A1.h[1] = swp ? wq[3][1] : wq[2][1];
  A1.h[2] = swp ? wq[2][0] : wq[3][0];
  A1.h[3] = swp ? wq[2][1] : wq[3][1];

  // ---- O^T += V^T P^T: A = V-frag (d=16nb+ln), B = P-frag ----
#pragma unroll
  for (int nb = 0; nb < 4; ++nb) {
    const int d   = nb * 16 + ln;
    const int dsw = (d >> 3) & 7;
    const f16* vbase = &Vt[d * KSTR];
    v8h v0 = *reinterpret_cast<const v8h*>(vbase + (((lq    ) ^ dsw) & 7) * 8);
    v8h v1 = *reinterpret_cast<const v8h*>(vbase + (((lq + 4) ^ dsw) & 7) * 8);
    st.o[nb] = __builtin_amdgcn_mfma_f32_16x16x32_f16(v0, A0.v, st.o[nb], 0, 0, 0);
    st.o[nb] = __builtin_amdgcn_mfma_f32_16x16x32_f16(v1, A1.v, st.o[nb], 0, 0, 0);
  }
}

extern "C" __global__ __launch_bounds__(256, 4)
void ftcca_sk(const float* __restrict__ Q,  const float* __restrict__ K,
              const float* __restrict__ V,  const float* __restrict__ Qd,
              const float* __restrict__ Kd, const float* __restrict__ Vd,
              float* __restrict__ ws,       float* __restrict__ out)
{
  __shared__ f16   Ks[64 * KSTR];
  __shared__ f16   Vt[64 * KSTR];       // V tile transposed [d][s], s-chunks XOR-swizzled
  __shared__ float zdiag[64];           // diag replacement scores (log2 units)
  __shared__ int   oldflag;

  // block mapping: u<16 -> split block (qt = 15-(u>>1), s = u&1); u>=16 -> unsplit qt=23-u
  const int g   = blockIdx.x;
  const int bh  = g & 63;
  const int u   = g >> 6;               // 0..23
  int qt, s;
  if (u < 16) { qt = 15 - (u >> 1); s = u & 1; }
  else        { qt = 23 - u;        s = -1;    }
  const bool split = (s >= 0);
  const bool drawn = split;             // split blocks are exactly the qt>=8 (l>=512) rows
  const int b   = bh >> 3, h = bh & 7;
  const int t   = threadIdx.x;
  const int w    = t >> 6;
  const int lane = t & 63;
  const int ln   = lane & 15;
  const int lq   = lane >> 4;
  const int rs   = t >> 2;              // K staging row 0..63
  const int es0  = (t & 3) * 16;        // K staging dim offset
  const int vr0  = (t >> 3) * 2;        // V staging row pair 0..62
  const int vd0  = (t & 7) * 8;         // V staging dim offset

  const size_t base = ((size_t)b * LL * HH + h) * EE;
  const int ROWF = HH * EE;             // 512

  // K-range for this block
  const int n  = qt + 1;
  const int i0 = (s == 1) ? (n >> 1) : 0;
  const int i1 = (s == 0) ? (n >> 1) : n;

  // sigma tables: K-frag read rows (indexed by ln) and owned-k bases (indexed by lq)
  const int q2 = ln >> 2;
  int rk[4], kb[4];
  rk[0] = ln + ((q2 + 1) >> 1) * 8;     // off[0] = {0,8,8,16}
  rk[1] = ln + 4 + (q2 >> 1) * 8;       // off[1] = {4,4,12,12}
  rk[2] = rk[0] + 32;
  rk[3] = rk[1] + 32;
  kb[0] = 4 * lq + ((lq + 1) >> 1) * 8;
  kb[1] = 4 * lq + 4 + (lq >> 1) * 8;
  kb[2] = kb[0] + 32;
  kb[3] = kb[1] + 32;

  // ---- zdiag (split1 only — it owns the diag tile): z[l][l] = SCALE2*(Qd[l].Kd[l]) ----
  if (s == 1) {
    const int l = qt * 64 + rs;
    const float* qrow = Qd + base + (size_t)l * ROWF + es0;
    const float* krow = Kd + base + (size_t)l * ROWF + es0;
    float par = 0.f;
#pragma unroll
    for (int i = 0; i < 16; ++i) par += qrow[i] * krow[i];
    par += __shfl_xor(par, 1);
    par += __shfl_xor(par, 2);
    if ((t & 3) == 0) zdiag[rs] = SCALE2 * par;
  }

  // ---- Q fragments (B-operand of QK^T: free-dim=ln, k=32c+8lq+j) ----
  const int qlocal = w * 16 + ln;
  const float* qsrc = drawn ? Qd : Q;
  v8h qf[2];
  {
    const float* pq = qsrc + base + (size_t)(qt * 64 + qlocal) * ROWF;
#pragma unroll
    for (int c = 0; c < 2; ++c) {
      const float* x = pq + 32 * c + 8 * lq;
#pragma unroll
      for (int j = 0; j < 8; ++j) qf[c][j] = (f16)x[j];
    }
  }

  TileState st;
#pragma unroll
  for (int nb = 0; nb < 4; ++nb) st.o[nb] = (v4f){0, 0, 0, 0};
  st.m = -1e30f; st.l = 0.f; st.pd = 0.f;

  // ---- prefetch K/V tile i0 into registers ----
  float tk[16], tv[16];
  load16f(K + base + (size_t)(i0 * 64 + rs) * ROWF + es0, tk);
  load8f(V + base + (size_t)(i0 * 64 + vr0) * ROWF + vd0, tv);
  load8f(V + base + (size_t)(i0 * 64 + vr0 + 1) * ROWF + vd0, tv + 8);

  for (int i = i0; i < i1; ++i) {
    __syncthreads();   // previous tile's LDS fully consumed
    {
      // commit register-staged tile i to LDS (f16)
      v8h k0, k1;
#pragma unroll
      for (int j = 0; j < 8; ++j) { k0[j] = (f16)tk[j]; k1[j] = (f16)tk[8 + j]; }
      v8h* kd0 = reinterpret_cast<v8h*>(&Ks[rs * KSTR + es0]);
      kd0[0] = k0;
      kd0[1] = k1;
      // V transposed: element (s=vr0+j, d) -> Vt[d*KSTR + ((s>>3)^(d>>3))*8 + (s&7)]
      const int vswz = vr0 >> 3;
#pragma unroll
      for (int dd = 0; dd < 8; ++dd) {
        const int d  = vd0 + dd;
        const int ch = (vswz ^ (d >> 3)) & 7;
        h2 val; val[0] = (f16)tv[dd]; val[1] = (f16)tv[8 + dd];
        *reinterpret_cast<h2*>(&Vt[d * KSTR + ch * 8 + (vr0 & 7)]) = val;
      }
    }
    __syncthreads();

    // issue next tile's global loads; they fly under this tile's compute
    if (i + 1 < i1) {
      const size_t r0 = (size_t)((i + 1) * 64);
      load16f(K + base + (r0 + rs) * ROWF + es0, tk);
      load8f(V + base + (r0 + vr0) * ROWF + vd0, tv);
      load8f(V + base + (r0 + vr0 + 1) * ROWF + vd0, tv + 8);
    }

    tile_update(st, qf, i == qt, drawn, Ks, Vt, zdiag, w, ln, lq, rk, kb);
  }

  const int lrow = qt * 64 + qlocal;

  if (!split) {
    // ---- unsplit epilogue (qt<=7: no drawn correction) ----
    const float inv = 1.f / st.l;
#pragma unroll
    for (int nb = 0; nb < 4; ++nb) {
      const int d0 = nb * 16 + lq * 4;
      const size_t gaddr = base + (size_t)lrow * ROWF + d0;
      float4 o4;
      o4.x = st.o[nb][0] * inv;
      o4.y = st.o[nb][1] * inv;
      o4.z = st.o[nb][2] * inv;
      o4.w = st.o[nb][3] * inv;
      *reinterpret_cast<float4*>(out + gaddr) = o4;
    }
    return;
  }

  // ---- split epilogue: publish partial, last arriver merges ----
  const int pair = (bh << 3) + (qt - 8);          // 0..511
  {
    float* Pm = ws + PBASE + (size_t)(pair * 2 + s) * PSTR;
#pragma unroll
    for (int nb = 0; nb < 4; ++nb) {
      float4 o4;
      o4.x = st.o[nb][0]; o4.y = st.o[nb][1]; o4.z = st.o[nb][2]; o4.w = st.o[nb][3];
      *reinterpret_cast<float4*>(&Pm[qlocal * 64 + nb * 16 + lq * 4]) = o4;
    }
    if (lq == 0) {
      Pm[4096 + qlocal] = st.m;
      Pm[4160 + qlocal] = st.l;
      Pm[4224 + qlocal] = st.pd;
    }
  }
  __threadfence();            // publish partial (device scope) before flag
  __syncthreads();            // all threads' writes before t0's atomic
  if (t == 0) oldflag = atomicAdd(reinterpret_cast<int*>(ws) + pair, 1);
  __syncthreads();
  if (oldflag == 0) return;   // first arriver: partner will merge

  __threadfence();            // acquire partner's partial
  const float* Pp = ws + PBASE + (size_t)(pair * 2 + (s ^ 1)) * PSTR;
  const float mb  = Pp[4096 + qlocal];
  const float lb  = Pp[4160 + qlocal];
  const float pdb = Pp[4224 + qlocal];

  const float mm = fmaxf(st.m, mb);
  const float ea = fexp2(st.m - mm);
  const float eb = fexp2(mb - mm);
  const float lt = st.l * ea + lb * eb;
  const float inv = 1.f / lt;
  const float pdinv = (st.pd * ea + pdb * eb) * inv;

#pragma unroll
  for (int nb = 0; nb < 4; ++nb) {
    const int d0 = nb * 16 + lq * 4;
    const size_t gaddr = base + (size_t)lrow * ROWF + d0;
    float4 ob = *reinterpret_cast<const float4*>(&Pp[qlocal * 64 + nb * 16 + lq * 4]);
    float4 vd4 = *reinterpret_cast<const float4*>(Vd + gaddr);
    float4 v4  = *reinterpret_cast<const float4*>(V + gaddr);
    float4 o4;
    o4.x = (st.o[nb][0] * ea + ob.x * eb) * inv + pdinv * (vd4.x - v4.x);
    o4.y = (st.o[nb][1] * ea + ob.y * eb) * inv + pdinv * (vd4.y - v4.y);
    o4.z = (st.o[nb][2] * ea + ob.z * eb) * inv + pdinv * (vd4.z - v4.z);
    o4.w = (st.o[nb][3] * ea + ob.w * eb) * inv + pdinv * (vd4.w - v4.w);
    *reinterpret_cast<float4*>(out + gaddr) = o4;
  }
}

extern "C" void kernel_launch(void* const* d_in, const int* in_sizes, int n_in,
                              void* d_out, int out_size, void* d_ws, size_t ws_size,
                              hipStream_t stream) {
  const float* q  = (const float*)d_in[0];
  const float* k  = (const float*)d_in[1];
  const float* v  = (const float*)d_in[2];
  const float* qd = (const float*)d_in[3];
  const float* kd = (const float*)d_in[4];
  const float* vd = (const float*)d_in[5];
  // d_in[6] = attn_mask (analytic), d_in[7] = history_len (HIST)
  float* out = (float*)d_out;
  float* ws  = (float*)d_ws;   // needs 4KB flags + 1024*17408B partials ~= 17.9 MB

  // zero the merge flags (graph-capture-safe; re-zeroed on every replay)
  hipMemsetAsync(d_ws, 0, 4096, stream);

  // 1536 blocks: 64 bh x (16 split-halves qt=8..15, big-first + 8 unsplit qt=7..0)
  ftcca_sk<<<dim3(1536), dim3(256), 0, stream>>>(q, k, v, qd, kd, vd, ws, out);
}

// Round 14
// 154.374 us; speedup vs baseline: 3.2812x; 2.4856x over previous
//
#include <hip/hip_runtime.h>

// FullFixedTimeCausalConstructiveAttention — MFMA flash, split blocks, swapped QK^T,
// in-register P (sigma), O^T layout, + CRITICAL-BLOCK PRIORITY (s_setprio).
// B=8, L=1024, H=8, E=64, HIST=512. Inputs fp32, output fp32.
// Layout: (b, l, h, e) row-major; per-(b,h) row stride = H*E = 512 floats.
//
// R14 = R4 (best verified, 44.5us) + s_setprio(1) for long blocks (qt>=12).
// Evidence: critical block's per-iter time ~6.7K cyc vs ~1.5K intrinsic chain;
// no pipe >35% busy -> its waves queue behind sibling blocks' waves (fair
// scheduler, but siblings have 4x slack). Priority makes the makespan block
// hog issue slots; short blocks fill the gaps. (R13 lesson: device-scope
// fences for in-kernel merge writeback non-coherent XCD L2s - never again.)
#define LL   1024
#define HH   8
#define EE   64
#define KSTR 72   // f16 LDS row stride: 144 B = 16B-aligned

#define SCALE2 0.18033688011112043f   // (1/sqrt(64)) * log2(e)

typedef _Float16 f16;
typedef _Float16 v8h  __attribute__((ext_vector_type(8)));
typedef _Float16 h2   __attribute__((ext_vector_type(2)));
typedef float    v4f  __attribute__((ext_vector_type(4)));
typedef int      v2i  __attribute__((ext_vector_type(2)));

__device__ __forceinline__ float fexp2(float x) {
#if __has_builtin(__builtin_amdgcn_exp2f)
  return __builtin_amdgcn_exp2f(x);
#else
  return __expf(x * 0.6931471805599453f);
#endif
}

__device__ __forceinline__ h2 pkh2(float a, float b) {
#if __has_builtin(__builtin_amdgcn_cvt_pkrtz)
  return __builtin_bit_cast(h2, __builtin_amdgcn_cvt_pkrtz(a, b));
#else
  h2 r; r[0] = (f16)a; r[1] = (f16)b; return r;
#endif
}

// Reduce across the 4 lane-quarters (lanes ln, ln+16, ln+32, ln+48).
__device__ __forceinline__ float red4max(float x) {
#if __has_builtin(__builtin_amdgcn_permlane16_swap) && __has_builtin(__builtin_amdgcn_permlane32_swap)
  int xi = __float_as_int(x);
  v2i a = __builtin_amdgcn_permlane16_swap(xi, xi, false, false);
  float m = fmaxf(__int_as_float(a.x), __int_as_float(a.y));
  int mi = __float_as_int(m);
  v2i b = __builtin_amdgcn_permlane32_swap(mi, mi, false, false);
  return fmaxf(__int_as_float(b.x), __int_as_float(b.y));
#else
  x = fmaxf(x, __shfl_xor(x, 16));
  return fmaxf(x, __shfl_xor(x, 32));
#endif
}

__device__ __forceinline__ float red4sum(float x) {
#if __has_builtin(__builtin_amdgcn_permlane16_swap) && __has_builtin(__builtin_amdgcn_permlane32_swap)
  int xi = __float_as_int(x);
  v2i a = __builtin_amdgcn_permlane16_swap(xi, xi, false, false);
  float s = __int_as_float(a.x) + __int_as_float(a.y);
  int si = __float_as_int(s);
  v2i b = __builtin_amdgcn_permlane32_swap(si, si, false, false);
  return __int_as_float(b.x) + __int_as_float(b.y);
#else
  x += __shfl_xor(x, 16);
  return x + __shfl_xor(x, 32);
#endif
}

__device__ __forceinline__ void load16f(const float* __restrict__ p, float* __restrict__ f) {
  const float4* p4 = reinterpret_cast<const float4*>(p);
  float4 a = p4[0], b = p4[1], c = p4[2], d = p4[3];
  f[0]=a.x;  f[1]=a.y;  f[2]=a.z;  f[3]=a.w;
  f[4]=b.x;  f[5]=b.y;  f[6]=b.z;  f[7]=b.w;
  f[8]=c.x;  f[9]=c.y;  f[10]=c.z; f[11]=c.w;
  f[12]=d.x; f[13]=d.y; f[14]=d.z; f[15]=d.w;
}

__device__ __forceinline__ void load8f(const float* __restrict__ p, float* __restrict__ f) {
  const float4* p4 = reinterpret_cast<const float4*>(p);
  float4 a = p4[0], b = p4[1];
  f[0]=a.x; f[1]=a.y; f[2]=a.z; f[3]=a.w;
  f[4]=b.x; f[5]=b.y; f[6]=b.z; f[7]=b.w;
}

struct TileState {
  v4f   o[4];      // O^T: lane holds O[d=16nb+4lq+r][q = tile_base + w*16 + ln]
  float m, l, pd;  // per-lane stats for q = ln
};

// One K-tile update. Lane (ln,lq) owns z[q=w*16+ln][s=sigma(nb,4lq+r)].
__device__ __forceinline__ void tile_update(
    TileState& st, const v8h* __restrict__ qf, bool dt, bool drawn,
    const f16* __restrict__ Ks, const f16* __restrict__ Vt,
    const float* __restrict__ zd,
    int w, int ln, int lq,
    const int* __restrict__ rk, const int* __restrict__ kb)
{
  // ---- S^T = K Q^T with permuted K rows: mfma nb, A-row m=ln <- K row rk[nb] ----
  v4f S[4];
#pragma unroll
  for (int nb = 0; nb < 4; ++nb) {
    const f16* krow = &Ks[rk[nb] * KSTR + 8 * lq];
    v8h k0 = *reinterpret_cast<const v8h*>(krow);
    v8h k1 = *reinterpret_cast<const v8h*>(krow + 32);
    v4f acc = (v4f){0.f, 0.f, 0.f, 0.f};
    acc = __builtin_amdgcn_mfma_f32_16x16x32_f16(k0, qf[0], acc, 0, 0, 0);
    acc = __builtin_amdgcn_mfma_f32_16x16x32_f16(k1, qf[1], acc, 0, 0, 0);
    S[nb] = acc;
  }

  float z[4][4];
#pragma unroll
  for (int nb = 0; nb < 4; ++nb)
#pragma unroll
    for (int r = 0; r < 4; ++r) z[nb][r] = S[nb][r] * SCALE2;

  const int qlocal = w * 16 + ln;
  if (dt) {
    const float zdq = drawn ? zd[qlocal] : 0.f;
#pragma unroll
    for (int nb = 0; nb < 4; ++nb) {
#pragma unroll
      for (int r = 0; r < 4; ++r) {
        const int kl = kb[nb] + r;             // sigma(nb, 4lq+r)
        if (kl > qlocal)                 z[nb][r] = -1e30f;  // causal mask
        else if (drawn && kl == qlocal)  z[nb][r] = zdq;     // diag replace
      }
    }
  }

  // ---- online softmax: local 16-tree + 2 permlane swaps (q=ln lane-local) ----
  float a0 = fmaxf(fmaxf(z[0][0], z[0][1]), fmaxf(z[0][2], z[0][3]));
  float a1 = fmaxf(fmaxf(z[1][0], z[1][1]), fmaxf(z[1][2], z[1][3]));
  float a2 = fmaxf(fmaxf(z[2][0], z[2][1]), fmaxf(z[2][2], z[2][3]));
  float a3 = fmaxf(fmaxf(z[3][0], z[3][1]), fmaxf(z[3][2], z[3][3]));
  const float mx = red4max(fmaxf(fmaxf(a0, a1), fmaxf(a2, a3)));

  const float mn = fmaxf(st.m, mx);
  const float al = fexp2(st.m - mn);
  st.m = mn;

  float p[4][4], rsum = 0.f, pdl = 0.f;
#pragma unroll
  for (int nb = 0; nb < 4; ++nb) {
#pragma unroll
    for (int r = 0; r < 4; ++r) {
      const float pv = fexp2(z[nb][r] - mn);
      p[nb][r] = pv;
      rsum += pv;
      if (dt && drawn && (kb[nb] + r) == qlocal) pdl = pv;
    }
  }
  rsum = red4sum(rsum);
  if (dt && drawn) st.pd = red4sum(pdl);   // diag tile is last: no later rescale
  st.l = st.l * al + rsum;
#pragma unroll
  for (int nb = 0; nb < 4; ++nb)
#pragma unroll
    for (int r = 0; r < 4; ++r) st.o[nb][r] *= al;   // per-lane scalar rescale

  // ---- P -> B-fragment in-register: owned pairs == needed k-layout by sigma ----
  h2 wq[4][2];
#pragma unroll
  for (int nb = 0; nb < 4; ++nb) {
    wq[nb][0] = pkh2(p[nb][0], p[nb][1]);
    wq[nb][1] = pkh2(p[nb][2], p[nb][3]);
  }
  const bool swp = (lq & 1);
  union U8 { v8h v; h2 h[4]; } A0, A1;
  A0.h[0] = swp ? wq[1][0] : wq[0][0];
  A0.h[1] = swp ? wq[1][1] : wq[0][1];
  A0.h[2] = swp ? wq[0][0] : wq[1][0];
  A0.h[3] = swp ? wq[0][1] : wq[1][1];
  A1.h[0] = swp ? wq[3][0] : wq[2][0];
  A1.h[1] = swp ? wq[3][1] : wq[2][1];
  A1.h[2] = swp ? wq[2][0] : wq[3][0];
  A1.h[3] = swp ? wq[2][1] : wq[3][1];

  // ---- O^T += V^T P^T: A = V-frag (d=16nb+ln), B = P-frag ----
#pragma unroll
  for (int nb = 0; nb < 4; ++nb) {
    const int d   = nb * 16 + ln;
    const int dsw = (d >> 3) & 7;
    const f16* vbase = &Vt[d * KSTR];
    v8h v0 = *reinterpret_cast<const v8h*>(vbase + (((lq    ) ^ dsw) & 7) * 8);
    v8h v1 = *reinterpret_cast<const v8h*>(vbase + (((lq + 4) ^ dsw) & 7) * 8);
    st.o[nb] = __builtin_amdgcn_mfma_f32_16x16x32_f16(v0, A0.v, st.o[nb], 0, 0, 0);
    st.o[nb] = __builtin_amdgcn_mfma_f32_16x16x32_f16(v1, A1.v, st.o[nb], 0, 0, 0);
  }
}

extern "C" __global__ __launch_bounds__(256, 4)
void ftcca_prio(const float* __restrict__ Q,  const float* __restrict__ K,
                const float* __restrict__ V,  const float* __restrict__ Qd,
                const float* __restrict__ Kd, const float* __restrict__ Vd,
                float* __restrict__ out)
{
  __shared__ f16   Ks[64 * KSTR];
  __shared__ f16   Vt[64 * KSTR];       // V tile transposed [d][s], s-chunks XOR-swizzled
  __shared__ float zdiag[64];           // diag replacement scores (log2 units)

  // bh = blockIdx & 63: all 16 q-tile blocks of one (b,h) land on one XCD -> K/V L2 reuse
  const int bh  = blockIdx.x & 63;
  const int a   = blockIdx.x >> 6;      // 0..15
  const int qt  = 15 - a;               // big K-ranges first
  const bool drawn = (qt >= 8);         // l >= 512 -> drawn rows
  const int b   = bh >> 3, h = bh & 7;
  const int t   = threadIdx.x;
  const int w    = t >> 6;
  const int lane = t & 63;
  const int ln   = lane & 15;
  const int lq   = lane >> 4;
  const int rs   = t >> 2;              // K staging row 0..63
  const int es0  = (t & 3) * 16;        // K staging dim offset
  const int vr0  = (t >> 3) * 2;        // V staging row pair 0..62
  const int vd0  = (t & 7) * 8;         // V staging dim offset

  // CRITICAL-BLOCK PRIORITY: long blocks (the makespan) hog CU issue slots;
  // short co-resident blocks have 4x slack and fill the gaps.
  if (qt >= 12) __builtin_amdgcn_s_setprio(1);

  const size_t base = ((size_t)b * LL * HH + h) * EE;
  const int ROWF = HH * EE;             // 512

  // sigma tables: K-frag read rows (indexed by ln) and owned-k bases (indexed by lq)
  const int q2 = ln >> 2;
  int rk[4], kb[4];
  rk[0] = ln + ((q2 + 1) >> 1) * 8;     // off[0] = {0,8,8,16}
  rk[1] = ln + 4 + (q2 >> 1) * 8;       // off[1] = {4,4,12,12}
  rk[2] = rk[0] + 32;
  rk[3] = rk[1] + 32;
  kb[0] = 4 * lq + ((lq + 1) >> 1) * 8;
  kb[1] = 4 * lq + 4 + (lq >> 1) * 8;
  kb[2] = kb[0] + 32;
  kb[3] = kb[1] + 32;

  // ---- zdiag (drawn tiles only): z[l][l] = SCALE2 * (Qd[l] . Kd[l]) ----
  if (drawn) {
    const int l = qt * 64 + rs;
    const float* qrow = Qd + base + (size_t)l * ROWF + es0;
    const float* krow = Kd + base + (size_t)l * ROWF + es0;
    float par = 0.f;
#pragma unroll
    for (int i = 0; i < 16; ++i) par += qrow[i] * krow[i];
    par += __shfl_xor(par, 1);
    par += __shfl_xor(par, 2);
    if ((t & 3) == 0) zdiag[rs] = SCALE2 * par;
  }

  // ---- Q fragments (B-operand of QK^T: free-dim=ln, k=32c+8lq+j) ----
  const int rowt_q = w * 16 + ln;
  const float* qsrc = drawn ? Qd : Q;
  v8h qf[2];
  {
    const float* pq = qsrc + base + (size_t)(qt * 64 + rowt_q) * ROWF;
#pragma unroll
    for (int c = 0; c < 2; ++c) {
      const float* x = pq + 32 * c + 8 * lq;
#pragma unroll
      for (int j = 0; j < 8; ++j) qf[c][j] = (f16)x[j];
    }
  }

  TileState st;
#pragma unroll
  for (int nb = 0; nb < 4; ++nb) st.o[nb] = (v4f){0, 0, 0, 0};
  st.m = -1e30f; st.l = 0.f; st.pd = 0.f;

  // ---- prefetch K/V tile 0 into registers ----
  float tk[16], tv[16];
  load16f(K + base + (size_t)rs * ROWF + es0, tk);
  load8f(V + base + (size_t)vr0 * ROWF + vd0, tv);
  load8f(V + base + (size_t)(vr0 + 1) * ROWF + vd0, tv + 8);

  for (int i = 0; i <= qt; ++i) {
    __syncthreads();   // previous tile's LDS fully consumed
    {
      // commit register-staged tile i to LDS (f16)
      v8h k0, k1;
#pragma unroll
      for (int j = 0; j < 8; ++j) { k0[j] = (f16)tk[j]; k1[j] = (f16)tk[8 + j]; }
      v8h* kd0 = reinterpret_cast<v8h*>(&Ks[rs * KSTR + es0]);
      kd0[0] = k0;
      kd0[1] = k1;
      // V transposed: element (s=vr0+j, d) -> Vt[d*KSTR + ((s>>3)^(d>>3))*8 + (s&7)]
      const int vswz = vr0 >> 3;
#pragma unroll
      for (int dd = 0; dd < 8; ++dd) {
        const int d  = vd0 + dd;
        const int ch = (vswz ^ (d >> 3)) & 7;
        h2 val; val[0] = (f16)tv[dd]; val[1] = (f16)tv[8 + dd];
        *reinterpret_cast<h2*>(&Vt[d * KSTR + ch * 8 + (vr0 & 7)]) = val;
      }
    }
    __syncthreads();

    // issue next tile's global loads; they fly under this tile's compute
    if (i < qt) {
      const size_t r0 = (size_t)((i + 1) * 64);
      load16f(K + base + (r0 + rs) * ROWF + es0, tk);
      load8f(V + base + (r0 + vr0) * ROWF + vd0, tv);
      load8f(V + base + (r0 + vr0 + 1) * ROWF + vd0, tv + 8);
    }

    tile_update(st, qf, i == qt, drawn, Ks, Vt, zdiag, w, ln, lq, rk, kb);
  }

  // ---- epilogue: O^T store — per-lane scalars, float4 per nb ----
  const float inv = 1.f / st.l;
  const float pdinv = st.pd * inv;
  const int lrow = qt * 64 + w * 16 + ln;

#pragma unroll
  for (int nb = 0; nb < 4; ++nb) {
    const int d0 = nb * 16 + lq * 4;
    const size_t g = base + (size_t)lrow * ROWF + d0;
    float4 o4;
    o4.x = st.o[nb][0] * inv;
    o4.y = st.o[nb][1] * inv;
    o4.z = st.o[nb][2] * inv;
    o4.w = st.o[nb][3] * inv;
    if (drawn) {
      float4 vd4 = *reinterpret_cast<const float4*>(Vd + g);
      float4 v4  = *reinterpret_cast<const float4*>(V + g);
      o4.x += pdinv * (vd4.x - v4.x);
      o4.y += pdinv * (vd4.y - v4.y);
      o4.z += pdinv * (vd4.z - v4.z);
      o4.w += pdinv * (vd4.w - v4.w);
    }
    *reinterpret_cast<float4*>(out + g) = o4;
  }
}

extern "C" void kernel_launch(void* const* d_in, const int* in_sizes, int n_in,
                              void* d_out, int out_size, void* d_ws, size_t ws_size,
                              hipStream_t stream) {
  const float* q  = (const float*)d_in[0];
  const float* k  = (const float*)d_in[1];
  const float* v  = (const float*)d_in[2];
  const float* qd = (const float*)d_in[3];
  const float* kd = (const float*)d_in[4];
  const float* vd = (const float*)d_in[5];
  // d_in[6] = attn_mask (analytic), d_in[7] = history_len (HIST)
  float* out = (float*)d_out;

  // 1024 blocks: 64 (b,h) x 16 q-tiles — 4 blocks/CU resident, big K-ranges first
  ftcca_prio<<<dim3(1024), dim3(256), 0, stream>>>(q, k, v, qd, kd, vd, out);
}